// Round 12
// baseline (75.597 us; speedup 1.0000x reference)
//
#include <hip/hip_runtime.h>
#include <math.h>

#define NB   4
#define CIN  512
#define HID  64
#define NK   11     // NUM_CLASSES+1
#define H1   60
#define W1p  80
#define P1   4800
#define H2   30
#define W2p  40
#define P2   1200
#define HO   480
#define WOp  640
#define NP1  (NB*P1)    // 19200
#define NP2  (NB*P2)    // 4800
#define PLANE ((size_t)HO*WOp)                  // 307200
#define SEG_OFF ((size_t)NB*NK*PLANE)           // 13,516,800
#define BBX_OFF (SEG_OFF + (size_t)NB*PLANE)    // 14,745,600

// ws layout in floats. Packed bf16 W-fragments = 6 parts x 32768 ushort
// = 196608 ushort = 98304 FLOATS (r11 bug: WS_C1=65536 aliased parts 4-5 ->
// f1 output writes clobbered f2's weight planes -> NaN).
#define WS_C1  98304                            // 19200*64 = 1,228,800
#define WS_F2  (WS_C1 + NP1*64)                 // 4800*64  =   307,200
#define WS_PRB (WS_F2 + NP2*64)                 // 19200*12 =   230,400
#define WS_SEG (WS_PRB + NP1*12)                // 19200 ints

typedef __attribute__((ext_vector_type(8))) short bf16x8;
typedef __attribute__((ext_vector_type(4))) float f32x4;

// RNE fp32 -> bf16, returns bits, writes residual x - bf16(x)
__device__ __forceinline__ unsigned short bfsplit(float x, float& resid) {
    unsigned u = __float_as_uint(x);
    unsigned t = u + 0x7FFFu + ((u >> 16) & 1u);
    unsigned short h = (unsigned short)(t >> 16);
    resid = x - __uint_as_float((unsigned)h << 16);
    return h;
}

// -------- pack weights into A-fragment order, 3-way bf16 split ---------------
// A-frag for mfma_f32_16x16x32_bf16: element (m,k): lane = m + 16*((k&31)>>3),
// j = k&7. Flat ushort index per part: ((mt*16+ks)*64 + lane)*8 + j.
// Parts: conv1 h,m,l then conv2 h,m,l (each 32768 ushort).
__global__ __launch_bounds__(256) void pack_w(const float* __restrict__ w1,
                                              const float* __restrict__ w2,
                                              float* __restrict__ ws) {
    int i = blockIdx.x * 256 + threadIdx.x;   // 0..32767
    if (i >= HID * CIN) return;
    int o = i >> 9;           // out-ch 0..63
    int c = i & 511;          // in-ch
    int d = (((o >> 4) * 16 + (c >> 5)) * 64 + (o & 15) + ((c >> 3) & 3) * 16) * 8 + (c & 7);
    unsigned short* q = (unsigned short*)ws;
    float r;
    float x = w1[i];
    unsigned short h = bfsplit(x, r);
    unsigned short m = bfsplit(r, r);
    unsigned short l = bfsplit(r, r);
    q[0 * 32768 + d] = h; q[1 * 32768 + d] = m; q[2 * 32768 + d] = l;
    x = w2[i];
    h = bfsplit(x, r); m = bfsplit(r, r); l = bfsplit(r, r);
    q[3 * 32768 + d] = h; q[4 * 32768 + d] = m; q[5 * 32768 + d] = l;
}

// -------- conv1x1 via MFMA, bf16x3 split (6-term, ~2^-24 accurate) ----------
// 192 blocks x 512 thr (8 waves). Block = 128-px tile, all 64 out-ch, K=512
// in 8 chunks of 64ch. Staging: coalesced fp32 loads -> 3-way bf16 split ->
// LDS int planes written in EXACT B-frag word order (stride-4B b32 ops).
// Wave wv = 16-px sub-tile: per k-step(32): B-frags = 12 ds_read_b32;
// A-frags = 12 dwordx4 (L2-resident packed W); 24 mfma. C/D layout (m89):
// col=lane&15 (pixel), row=(lane>>4)*4+reg (out-ch) -> strided float4 stores.
__global__ __launch_bounds__(512) void conv_mfma(const float* __restrict__ f1,
                                                 const float* __restrict__ f2,
                                                 const float* __restrict__ b1v,
                                                 const float* __restrict__ b2v,
                                                 const float* __restrict__ wsbase,
                                                 float* __restrict__ c1o,
                                                 float* __restrict__ f2o) {
    __shared__ int xpl[3 * 4096];   // [part][pt 8][ks2 2][word 4][lane 64], 48KB
    int t = blockIdx.x;
    const float* X; const unsigned short* WPK; const float* bias; float* Cout;
    int P, px0;
    const unsigned short* q = (const unsigned short*)wsbase;
    if (t < 152) {                  // f1: 4 batches x 38 tiles
        int b = t / 38, ti = t % 38;
        px0 = ti * 128; if (px0 > P1 - 128) px0 = P1 - 128;   // overlap tail (dup stores benign)
        X = f1 + (size_t)b * CIN * P1;  P = P1;  WPK = q;  bias = b1v;
        Cout = c1o + (size_t)b * P1 * 64;
    } else {                        // f2: 4 batches x 10 tiles
        int u = t - 152; int b = u / 10, ti = u % 10;
        px0 = ti * 128; if (px0 > P2 - 128) px0 = P2 - 128;
        X = f2 + (size_t)b * CIN * P2;  P = P2;  WPK = q + 3 * 32768;  bias = b2v;
        Cout = f2o + (size_t)b * P2 * 64;
    }
    int tid  = threadIdx.x;
    int lane = tid & 63;
    int wv   = tid >> 6;            // 0..7 = 16-px sub-tile
    int chg  = tid >> 7;            // staging: 0..3
    int px_s = tid & 127;           // staging pixel
    int pt_s = px_s >> 4, pcol = px_s & 15;

    f32x4 acc[4];
#pragma unroll
    for (int mt = 0; mt < 4; ++mt) acc[mt] = (f32x4){0.f, 0.f, 0.f, 0.f};

    float xv[16];
    const float* gbase = X + px0 + px_s;

    // ---- prologue: load + stage chunk 0 ----
#pragma unroll
    for (int i = 0; i < 8; ++i) {
        int chl = 2 * (chg + 4 * i);
        xv[2 * i]     = gbase[(size_t)chl * P];
        xv[2 * i + 1] = gbase[(size_t)(chl + 1) * P];
    }
#pragma unroll
    for (int i = 0; i < 8; ++i) {
        int chl = 2 * (chg + 4 * i);
        int ks2 = chl >> 5, kk = chl & 31;
        int base = pt_s * 512 + ks2 * 256 + ((kk & 7) >> 1) * 64 + pcol + ((kk >> 3) & 3) * 16;
        float r;
        unsigned short h0 = bfsplit(xv[2*i], r), m0 = bfsplit(r, r), l0 = bfsplit(r, r);
        unsigned short h1 = bfsplit(xv[2*i+1], r), m1 = bfsplit(r, r), l1 = bfsplit(r, r);
        xpl[base]        = (int)h0 | ((int)h1 << 16);
        xpl[4096 + base] = (int)m0 | ((int)m1 << 16);
        xpl[8192 + base] = (int)l0 | ((int)l1 << 16);
    }
    __syncthreads();

    union FragU { int i[4]; bf16x8 v; };

    for (int c = 0; c < 8; ++c) {
        // issue next chunk's global loads (latency hides under mfma)
        if (c < 7) {
            const float* g = gbase + (size_t)((c + 1) * 64) * P;
#pragma unroll
            for (int i = 0; i < 8; ++i) {
                int chl = 2 * (chg + 4 * i);
                xv[2 * i]     = g[(size_t)chl * P];
                xv[2 * i + 1] = g[(size_t)(chl + 1) * P];
            }
        }
        // compute chunk c
#pragma unroll
        for (int ks2 = 0; ks2 < 2; ++ks2) {
            FragU Bh, Bm, Bl;
            int bb = wv * 512 + ks2 * 256 + lane;
#pragma unroll
            for (int w = 0; w < 4; ++w) {
                Bh.i[w] = xpl[bb + w * 64];
                Bm.i[w] = xpl[4096 + bb + w * 64];
                Bl.i[w] = xpl[8192 + bb + w * 64];
            }
            int ks = c * 2 + ks2;
#pragma unroll
            for (int mt = 0; mt < 4; ++mt) {
                size_t ao = ((size_t)(mt * 16 + ks) * 64 + lane) * 8;
                bf16x8 Ah = *(const bf16x8*)(WPK + ao);
                bf16x8 Am = *(const bf16x8*)(WPK + 32768 + ao);
                bf16x8 Al = *(const bf16x8*)(WPK + 65536 + ao);
                acc[mt] = __builtin_amdgcn_mfma_f32_16x16x32_bf16(Ah, Bh.v, acc[mt], 0, 0, 0);
                acc[mt] = __builtin_amdgcn_mfma_f32_16x16x32_bf16(Ah, Bm.v, acc[mt], 0, 0, 0);
                acc[mt] = __builtin_amdgcn_mfma_f32_16x16x32_bf16(Am, Bh.v, acc[mt], 0, 0, 0);
                acc[mt] = __builtin_amdgcn_mfma_f32_16x16x32_bf16(Ah, Bl.v, acc[mt], 0, 0, 0);
                acc[mt] = __builtin_amdgcn_mfma_f32_16x16x32_bf16(Am, Bm.v, acc[mt], 0, 0, 0);
                acc[mt] = __builtin_amdgcn_mfma_f32_16x16x32_bf16(Al, Bh.v, acc[mt], 0, 0, 0);
            }
        }
        __syncthreads();
        if (c < 7) {
#pragma unroll
            for (int i = 0; i < 8; ++i) {
                int chl = 2 * (chg + 4 * i);
                int ks2 = chl >> 5, kk = chl & 31;
                int base = pt_s * 512 + ks2 * 256 + ((kk & 7) >> 1) * 64 + pcol + ((kk >> 3) & 3) * 16;
                float r;
                unsigned short h0 = bfsplit(xv[2*i], r), m0 = bfsplit(r, r), l0 = bfsplit(r, r);
                unsigned short h1 = bfsplit(xv[2*i+1], r), m1 = bfsplit(r, r), l1 = bfsplit(r, r);
                xpl[base]        = (int)h0 | ((int)h1 << 16);
                xpl[4096 + base] = (int)m0 | ((int)m1 << 16);
                xpl[8192 + base] = (int)l0 | ((int)l1 << 16);
            }
        }
        __syncthreads();
    }

    // ---- epilogue: bias + relu + store [px][64] fp32 ----
    int px = px0 + wv * 16 + (lane & 15);
    int g4 = (lane >> 4) * 4;
    float* op = Cout + (size_t)px * 64;
#pragma unroll
    for (int mt = 0; mt < 4; ++mt) {
        float4 bb = *(const float4*)(bias + mt * 16 + g4);
        float a0 = acc[mt][0] + bb.x;
        float a1 = acc[mt][1] + bb.y;
        float a2 = acc[mt][2] + bb.z;
        float a3 = acc[mt][3] + bb.w;
        *(float4*)(op + mt * 16 + g4) =
            make_float4(a0 > 0.f ? a0 : 0.f, a1 > 0.f ? a1 : 0.f,
                        a2 > 0.f ? a2 : 0.f, a3 > 0.f ? a3 : 0.f);
    }
}

// ---------------- head: add feat2-up, wo conv, softmax, argmax -> prb/seg ---
__global__ __launch_bounds__(256) void head_kernel(const float* __restrict__ wo,
                                                   const float* __restrict__ bo,
                                                   float* __restrict__ ws) {
    __shared__ float swo[NK * 64];
    __shared__ float sbo[NK];
    for (int i = threadIdx.x; i < NK * 64; i += 256) swo[i] = wo[i];
    if (threadIdx.x < NK) sbo[threadIdx.x] = bo[threadIdx.x];
    __syncthreads();

    int p  = blockIdx.x * 256 + threadIdx.x;   // 0..19199
    int b  = p / P1;
    int pb = p % P1;
    int y  = pb / W1p, x = pb % W1p;
    int qp = (y >> 1) * W2p + (x >> 1);
    const float* c1p = ws + WS_C1 + ((size_t)b * P1 + pb) * 64;
    const float* f2p = ws + WS_F2 + ((size_t)b * P2 + qp) * 64;

    float ok[NK];
#pragma unroll
    for (int k = 0; k < NK; ++k) ok[k] = sbo[k];
#pragma unroll
    for (int o4 = 0; o4 < 16; ++o4) {
        float4 c1q = *(const float4*)(c1p + o4 * 4);
        float4 f2q = *(const float4*)(f2p + o4 * 4);
        float co[4] = { c1q.x + f2q.x, c1q.y + f2q.y, c1q.z + f2q.z, c1q.w + f2q.w };
#pragma unroll
        for (int j = 0; j < 4; ++j) {
            int o = o4 * 4 + j;
#pragma unroll
            for (int k = 0; k < NK; ++k) ok[k] = fmaf(co[j], swo[k * 64 + o], ok[k]);
        }
    }
    float m = 0.f;
#pragma unroll
    for (int k = 0; k < NK; ++k) {
        ok[k] = ok[k] > 0.f ? ok[k] : 0.f;          // relu(out)
        if (ok[k] > m) m = ok[k];
    }
    float e[NK], sum = 0.f;
#pragma unroll
    for (int k = 0; k < NK; ++k) { e[k] = expf(ok[k] - m); sum += e[k]; }
    float inv = 1.f / sum;
    int arg = 0; float best = ok[0];
#pragma unroll
    for (int k = 1; k < NK; ++k) { if (ok[k] > best) { best = ok[k]; arg = k; } }

    float* pr = ws + WS_PRB + (size_t)p * 12;
#pragma unroll
    for (int k = 0; k < NK; ++k) pr[k] = e[k] * inv;
    pr[11] = (float)arg;
    ((int*)(ws + WS_SEG))[p] = arg;
}

// ---------------- upsample 8x: pure streaming replicate-store ----------------
__global__ __launch_bounds__(256) void upsample_kernel(const float* __restrict__ ws,
                                                       float* __restrict__ out) {
    const float* prb = ws + WS_PRB;
    unsigned total4 = (unsigned)((SEG_OFF + (size_t)NB * PLANE) / 4);  // 3,686,400
    unsigned step = gridDim.x * 256;
    for (unsigned i4 = blockIdx.x * 256 + threadIdx.x; i4 < total4; i4 += step) {
        unsigned f = i4 * 4;
        float v;
        if (f < (unsigned)SEG_OFF) {
            unsigned plane = f / (unsigned)PLANE;      // 0..43
            unsigned r = f - plane * (unsigned)PLANE;
            unsigned b = plane / NK, k = plane - b * NK;
            unsigned y = r / WOp, x = r - y * WOp;
            unsigned p = b * P1 + (y >> 3) * W1p + (x >> 3);
            v = prb[p * 12 + k];
        } else {
            unsigned g = f - (unsigned)SEG_OFF;
            unsigned b = g / (unsigned)PLANE;
            unsigned r = g - b * (unsigned)PLANE;
            unsigned y = r / WOp, x = r - y * WOp;
            unsigned p = b * P1 + (y >> 3) * W1p + (x >> 3);
            v = prb[p * 12 + 11];
        }
        *(float4*)(out + f) = make_float4(v, v, v, v);
    }
}

// ---------------- bbox: per-(batch,class) min/max/count over 60x80 seg ------
__global__ __launch_bounds__(256) void bbx_kernel(const float* __restrict__ ws,
                                                  float* __restrict__ out) {
    __shared__ int cnt[10], xmn[10], xmx[10], ymn[10], ymx[10];
    int b = blockIdx.x;
    int t = threadIdx.x;
    if (t < 10) { cnt[t] = 0; xmn[t] = 1 << 30; xmx[t] = -1; ymn[t] = 1 << 30; ymx[t] = -1; }
    __syncthreads();
    const int* seg = (const int*)(ws + WS_SEG) + b * P1;
    for (int p = t; p < P1; p += 256) {
        int s = seg[p];
        if (s >= 1 && s <= 9) {
            int y = p / W1p, x = p % W1p;
            atomicAdd(&cnt[s], 1);
            atomicMin(&xmn[s], x); atomicMax(&xmx[s], x);
            atomicMin(&ymn[s], y); atomicMax(&ymx[s], y);
        }
    }
    __syncthreads();
    if (t < 9) {
        int c = t + 1;
        bool valid = cnt[c] * 64 >= 500;    // upsampled count = 64*count
        float r[6];
        if (valid) {
            r[0] = (float)b;
            r[1] = (float)(xmn[c] * 8);
            r[2] = (float)(ymn[c] * 8);
            r[3] = (float)(xmx[c] * 8 + 7);
            r[4] = (float)(ymx[c] * 8 + 7);
            r[5] = (float)c;
        } else {
            for (int i = 0; i < 6; ++i) r[i] = -1.f;
        }
        float* row = out + BBX_OFF + (size_t)(b * 9 + t) * 6;
        for (int i = 0; i < 6; ++i) row[i] = r[i];
    }
}

extern "C" void kernel_launch(void* const* d_in, const int* in_sizes, int n_in,
                              void* d_out, int out_size, void* d_ws, size_t ws_size,
                              hipStream_t stream) {
    const float* f1 = (const float*)d_in[0];
    const float* f2 = (const float*)d_in[1];
    const float* w1 = (const float*)d_in[2];
    const float* b1 = (const float*)d_in[3];
    const float* w2 = (const float*)d_in[4];
    const float* b2 = (const float*)d_in[5];
    const float* wo = (const float*)d_in[6];
    const float* bo = (const float*)d_in[7];
    float* ws  = (float*)d_ws;
    float* out = (float*)d_out;

    pack_w<<<128, 256, 0, stream>>>(w1, w2, ws);
    conv_mfma<<<192, 512, 0, stream>>>(f1, f2, b1, b2, ws,
                                       ws + WS_C1, ws + WS_F2);
    head_kernel<<<75, 256, 0, stream>>>(wo, bo, ws);
    upsample_kernel<<<2048, 256, 0, stream>>>(ws, out);
    bbx_kernel<<<NB, 256, 0, stream>>>(ws, out);
}

// Round 13
// 66.852 us; speedup vs baseline: 1.1308x; 1.1308x over previous
//
#include <hip/hip_runtime.h>
#include <math.h>

#define NB   4
#define CIN  512
#define HID  64
#define NK   11     // NUM_CLASSES+1
#define H1   60
#define W1p  80
#define P1   4800
#define H2   30
#define W2p  40
#define P2   1200
#define HO   480
#define WOp  640
#define NP1  (NB*P1)    // 19200
#define NP2  (NB*P2)    // 4800
#define PLANE ((size_t)HO*WOp)                  // 307200
#define SEG_OFF ((size_t)NB*NK*PLANE)           // 13,516,800
#define BBX_OFF (SEG_OFF + (size_t)NB*PLANE)    // 14,745,600

// ws layout in floats. Packed bf16 W-fragments: 2 convs x 2 planes x 32768
// ushort = 131072 ushort = 65536 floats.
#define WS_C1  65536                            // 19200*64 = 1,228,800
#define WS_F2  (WS_C1 + NP1*64)                 // 4800*64  =   307,200
#define WS_PRB (WS_F2 + NP2*64)                 // 19200*12 =   230,400
#define WS_SEG (WS_PRB + NP1*12)                // 19200 ints

typedef __attribute__((ext_vector_type(8))) short bf16x8;
typedef __attribute__((ext_vector_type(4))) float f32x4;

// RNE fp32 -> bf16, returns bits, writes residual x - bf16(x)
__device__ __forceinline__ unsigned short bfsplit(float x, float& resid) {
    unsigned u = __float_as_uint(x);
    unsigned t = u + 0x7FFFu + ((u >> 16) & 1u);
    unsigned short h = (unsigned short)(t >> 16);
    resid = x - __uint_as_float((unsigned)h << 16);
    return h;
}

// -------- pack weights into chunk-major A-fragment pages, 2-plane split -----
// ushort idx = ((((chunk*2+ks2)*4+mt)*2+plane)*64 + lane)*8 + j
// lane = (o&15) + 16*(k>>3), j = k&7, mt = o>>4  (k = in-ch & 31 within ks2).
// Per conv: 65536 ushort. conv2 at +65536.
__global__ __launch_bounds__(256) void pack_w(const float* __restrict__ w1,
                                              const float* __restrict__ w2,
                                              float* __restrict__ ws) {
    int i = blockIdx.x * 256 + threadIdx.x;   // 0..32767
    if (i >= HID * CIN) return;
    int o = i >> 9, c = i & 511;
    int chunk = c >> 6, r = c & 63, ks2 = r >> 5, k = r & 31;
    int lane = (o & 15) + ((k >> 3) << 4);
    int mt = o >> 4;
    int d = ((((chunk * 2 + ks2) * 4 + mt) * 2) * 64 + lane) * 8 + (k & 7);
    unsigned short* q = (unsigned short*)ws;
    float r1;
    unsigned short h = bfsplit(w1[i], r1);
    unsigned short m = bfsplit(r1, r1);
    q[d] = h; q[d + 512] = m;                 // plane stride = 64*8 = 512
    h = bfsplit(w2[i], r1); m = bfsplit(r1, r1);
    q[65536 + d] = h; q[65536 + d + 512] = m;
}

// -------- conv1x1 via MFMA v13: LDS A-frags + slot-owner staging ------------
// 376 blocks x 256 thr (4 waves). Block = 64-px tile, 64 out-ch, K=512 in 8
// chunks of 64. r12 lesson: per-wave A-frag re-reads from L2 (300MB aggregate,
// no prefetch) were the 80% stall + 590K bank conflicts from staging writes.
// Now: A-frags LDS-staged once per chunk (16KB, prefetched 1 ahead in regs);
// X staged as 2-plane bf16 split (4-term mfma: err ~2^-18 rel); staging thread
// = one fragment slot (lane=slot, wave=pt) so ALL ds ops are the canonical
// conflict-free lane*16B b128 pattern. X loads prefetched 2 chunks ahead.
__global__ __launch_bounds__(256) void conv_mfma(const float* __restrict__ f1,
                                                 const float* __restrict__ f2,
                                                 const float* __restrict__ b1v,
                                                 const float* __restrict__ b2v,
                                                 const float* __restrict__ wsbase,
                                                 float* __restrict__ c1o,
                                                 float* __restrict__ f2o) {
    __shared__ int xpl[16 * 256];    // [pt4][ks2 2][plane2][slot64][word4] 16KB
    __shared__ int alds[16 * 256];   // [ks2 2][mt4][plane2][lane64][word4] 16KB
    int t = blockIdx.x;
    const float* X; const float* bias; float* Cout; const int* WPK;
    int P, px0;
    const unsigned short* q = (const unsigned short*)wsbase;
    if (t < 300) {
        int b = t / 75, ti = t % 75;
        px0 = ti * 64;
        X = f1 + (size_t)b * CIN * P1;  P = P1;  bias = b1v;
        WPK = (const int*)q;
        Cout = c1o + (size_t)b * P1 * 64;
    } else {
        int u = t - 300; int b = u / 19, ti = u % 19;
        px0 = ti * 64; if (px0 > P2 - 64) px0 = P2 - 64;  // tail overlap benign
        X = f2 + (size_t)b * CIN * P2;  P = P2;  bias = b2v;
        WPK = (const int*)(q + 65536);
        Cout = f2o + (size_t)b * P2 * 64;
    }
    int tid  = threadIdx.x;
    int lane = tid & 63;
    int wv   = tid >> 6;              // staging pt AND compute mt AND epilogue mt
    int pcol = lane & 15, kgrp = lane >> 4;

    const float* Xg = X + px0 + wv * 16 + pcol;   // this thread's pixel

    float xvA[16], xvB[16];
    int4 areg[4];

    auto loadX = [&](float* dst, int cc) {
#pragma unroll
        for (int ks2 = 0; ks2 < 2; ++ks2)
#pragma unroll
            for (int j = 0; j < 8; ++j) {
                int ch = cc * 64 + ks2 * 32 + kgrp * 8 + j;
                dst[ks2 * 8 + j] = Xg[(size_t)ch * P];
            }
    };
    auto loadA = [&](int cc) {
#pragma unroll
        for (int p = 0; p < 4; ++p)
            areg[p] = *(const int4*)&WPK[cc * 4096 + p * 1024 + tid * 4];
    };
    auto stage = [&](const float* xs) {
#pragma unroll
        for (int ks2 = 0; ks2 < 2; ++ks2) {
            int hh[8], mm[8];
#pragma unroll
            for (int j = 0; j < 8; ++j) {
                float r;
                unsigned short h = bfsplit(xs[ks2 * 8 + j], r);
                unsigned short m = bfsplit(r, r);
                hh[j] = h; mm[j] = m;
            }
            int4 H, M;
            ((int*)&H)[0] = hh[0] | (hh[1] << 16);
            ((int*)&H)[1] = hh[2] | (hh[3] << 16);
            ((int*)&H)[2] = hh[4] | (hh[5] << 16);
            ((int*)&H)[3] = hh[6] | (hh[7] << 16);
            ((int*)&M)[0] = mm[0] | (mm[1] << 16);
            ((int*)&M)[1] = mm[2] | (mm[3] << 16);
            ((int*)&M)[2] = mm[4] | (mm[5] << 16);
            ((int*)&M)[3] = mm[6] | (mm[7] << 16);
            int pg = ((wv * 2 + ks2) * 2) * 256 + lane * 4;
            *(int4*)&xpl[pg]       = H;
            *(int4*)&xpl[pg + 256] = M;
        }
#pragma unroll
        for (int p = 0; p < 4; ++p)
            *(int4*)&alds[p * 1024 + tid * 4] = areg[p];
    };

    union FU { int4 q; bf16x8 v; };
    f32x4 acc[4];
#pragma unroll
    for (int st = 0; st < 4; ++st) acc[st] = (f32x4){0.f, 0.f, 0.f, 0.f};

    // prologue: chunk 0 staged; chunk 1 X in flight
    loadX(xvA, 0);
    loadA(0);
    stage(xvA);
    loadX(xvA, 1);
    __syncthreads();

    for (int c = 0; c < 8; ++c) {
        if (c < 7) loadA(c + 1);
        if (c < 6) loadX(xvB, c + 2);
        // compute chunk c
#pragma unroll
        for (int ks2 = 0; ks2 < 2; ++ks2) {
            FU Ah, Am;
            int pa = ((ks2 * 4 + wv) * 2) * 256 + lane * 4;
            Ah.q = *(const int4*)&alds[pa];
            Am.q = *(const int4*)&alds[pa + 256];
#pragma unroll
            for (int st = 0; st < 4; ++st) {
                FU Bh, Bm;
                int pb = ((st * 2 + ks2) * 2) * 256 + lane * 4;
                Bh.q = *(const int4*)&xpl[pb];
                Bm.q = *(const int4*)&xpl[pb + 256];
                acc[st] = __builtin_amdgcn_mfma_f32_16x16x32_bf16(Ah.v, Bh.v, acc[st], 0, 0, 0);
                acc[st] = __builtin_amdgcn_mfma_f32_16x16x32_bf16(Ah.v, Bm.v, acc[st], 0, 0, 0);
                acc[st] = __builtin_amdgcn_mfma_f32_16x16x32_bf16(Am.v, Bh.v, acc[st], 0, 0, 0);
                acc[st] = __builtin_amdgcn_mfma_f32_16x16x32_bf16(Am.v, Bm.v, acc[st], 0, 0, 0);
            }
        }
        __syncthreads();
        if (c < 7) {
            stage(xvA);
            __syncthreads();
#pragma unroll
            for (int i2 = 0; i2 < 16; ++i2) xvA[i2] = xvB[i2];
        }
    }

    // epilogue: C/D layout col=lane&15 (px-in-st), row=(lane>>4)*4+reg (out-ch)
    int r4 = (lane >> 4) * 4;
    float4 bb = *(const float4*)(bias + wv * 16 + r4);
#pragma unroll
    for (int st = 0; st < 4; ++st) {
        int px = px0 + st * 16 + pcol;
        float a0 = acc[st][0] + bb.x;
        float a1 = acc[st][1] + bb.y;
        float a2 = acc[st][2] + bb.z;
        float a3 = acc[st][3] + bb.w;
        *(float4*)(Cout + (size_t)px * 64 + wv * 16 + r4) =
            make_float4(a0 > 0.f ? a0 : 0.f, a1 > 0.f ? a1 : 0.f,
                        a2 > 0.f ? a2 : 0.f, a3 > 0.f ? a3 : 0.f);
    }
}

// ---------------- head: add feat2-up, wo conv, softmax, argmax -> prb/seg ---
__global__ __launch_bounds__(256) void head_kernel(const float* __restrict__ wo,
                                                   const float* __restrict__ bo,
                                                   float* __restrict__ ws) {
    __shared__ float swo[NK * 64];
    __shared__ float sbo[NK];
    for (int i = threadIdx.x; i < NK * 64; i += 256) swo[i] = wo[i];
    if (threadIdx.x < NK) sbo[threadIdx.x] = bo[threadIdx.x];
    __syncthreads();

    int p  = blockIdx.x * 256 + threadIdx.x;   // 0..19199
    int b  = p / P1;
    int pb = p % P1;
    int y  = pb / W1p, x = pb % W1p;
    int qp = (y >> 1) * W2p + (x >> 1);
    const float* c1p = ws + WS_C1 + ((size_t)b * P1 + pb) * 64;
    const float* f2p = ws + WS_F2 + ((size_t)b * P2 + qp) * 64;

    float ok[NK];
#pragma unroll
    for (int k = 0; k < NK; ++k) ok[k] = sbo[k];
#pragma unroll
    for (int o4 = 0; o4 < 16; ++o4) {
        float4 c1q = *(const float4*)(c1p + o4 * 4);
        float4 f2q = *(const float4*)(f2p + o4 * 4);
        float co[4] = { c1q.x + f2q.x, c1q.y + f2q.y, c1q.z + f2q.z, c1q.w + f2q.w };
#pragma unroll
        for (int j = 0; j < 4; ++j) {
            int o = o4 * 4 + j;
#pragma unroll
            for (int k = 0; k < NK; ++k) ok[k] = fmaf(co[j], swo[k * 64 + o], ok[k]);
        }
    }
    float m = 0.f;
#pragma unroll
    for (int k = 0; k < NK; ++k) {
        ok[k] = ok[k] > 0.f ? ok[k] : 0.f;          // relu(out)
        if (ok[k] > m) m = ok[k];
    }
    float e[NK], sum = 0.f;
#pragma unroll
    for (int k = 0; k < NK; ++k) { e[k] = expf(ok[k] - m); sum += e[k]; }
    float inv = 1.f / sum;
    int arg = 0; float best = ok[0];
#pragma unroll
    for (int k = 1; k < NK; ++k) { if (ok[k] > best) { best = ok[k]; arg = k; } }

    float* pr = ws + WS_PRB + (size_t)p * 12;
#pragma unroll
    for (int k = 0; k < NK; ++k) pr[k] = e[k] * inv;
    pr[11] = (float)arg;
    ((int*)(ws + WS_SEG))[p] = arg;
}

// ---------------- upsample 8x: pure streaming replicate-store ----------------
__global__ __launch_bounds__(256) void upsample_kernel(const float* __restrict__ ws,
                                                       float* __restrict__ out) {
    const float* prb = ws + WS_PRB;
    unsigned total4 = (unsigned)((SEG_OFF + (size_t)NB * PLANE) / 4);  // 3,686,400
    unsigned step = gridDim.x * 256;
    for (unsigned i4 = blockIdx.x * 256 + threadIdx.x; i4 < total4; i4 += step) {
        unsigned f = i4 * 4;
        float v;
        if (f < (unsigned)SEG_OFF) {
            unsigned plane = f / (unsigned)PLANE;      // 0..43
            unsigned r = f - plane * (unsigned)PLANE;
            unsigned b = plane / NK, k = plane - b * NK;
            unsigned y = r / WOp, x = r - y * WOp;
            unsigned p = b * P1 + (y >> 3) * W1p + (x >> 3);
            v = prb[p * 12 + k];
        } else {
            unsigned g = f - (unsigned)SEG_OFF;
            unsigned b = g / (unsigned)PLANE;
            unsigned r = g - b * (unsigned)PLANE;
            unsigned y = r / WOp, x = r - y * WOp;
            unsigned p = b * P1 + (y >> 3) * W1p + (x >> 3);
            v = prb[p * 12 + 11];
        }
        *(float4*)(out + f) = make_float4(v, v, v, v);
    }
}

// ---------------- bbox: per-(batch,class) min/max/count over 60x80 seg ------
__global__ __launch_bounds__(256) void bbx_kernel(const float* __restrict__ ws,
                                                  float* __restrict__ out) {
    __shared__ int cnt[10], xmn[10], xmx[10], ymn[10], ymx[10];
    int b = blockIdx.x;
    int t = threadIdx.x;
    if (t < 10) { cnt[t] = 0; xmn[t] = 1 << 30; xmx[t] = -1; ymn[t] = 1 << 30; ymx[t] = -1; }
    __syncthreads();
    const int* seg = (const int*)(ws + WS_SEG) + b * P1;
    for (int p = t; p < P1; p += 256) {
        int s = seg[p];
        if (s >= 1 && s <= 9) {
            int y = p / W1p, x = p % W1p;
            atomicAdd(&cnt[s], 1);
            atomicMin(&xmn[s], x); atomicMax(&xmx[s], x);
            atomicMin(&ymn[s], y); atomicMax(&ymx[s], y);
        }
    }
    __syncthreads();
    if (t < 9) {
        int c = t + 1;
        bool valid = cnt[c] * 64 >= 500;    // upsampled count = 64*count
        float r[6];
        if (valid) {
            r[0] = (float)b;
            r[1] = (float)(xmn[c] * 8);
            r[2] = (float)(ymn[c] * 8);
            r[3] = (float)(xmx[c] * 8 + 7);
            r[4] = (float)(ymx[c] * 8 + 7);
            r[5] = (float)c;
        } else {
            for (int i = 0; i < 6; ++i) r[i] = -1.f;
        }
        float* row = out + BBX_OFF + (size_t)(b * 9 + t) * 6;
        for (int i = 0; i < 6; ++i) row[i] = r[i];
    }
}

extern "C" void kernel_launch(void* const* d_in, const int* in_sizes, int n_in,
                              void* d_out, int out_size, void* d_ws, size_t ws_size,
                              hipStream_t stream) {
    const float* f1 = (const float*)d_in[0];
    const float* f2 = (const float*)d_in[1];
    const float* w1 = (const float*)d_in[2];
    const float* b1 = (const float*)d_in[3];
    const float* w2 = (const float*)d_in[4];
    const float* b2 = (const float*)d_in[5];
    const float* wo = (const float*)d_in[6];
    const float* bo = (const float*)d_in[7];
    float* ws  = (float*)d_ws;
    float* out = (float*)d_out;

    pack_w<<<128, 256, 0, stream>>>(w1, w2, ws);
    conv_mfma<<<376, 256, 0, stream>>>(f1, f2, b1, b2, ws,
                                       ws + WS_C1, ws + WS_F2);
    head_kernel<<<75, 256, 0, stream>>>(wo, bo, ws);
    upsample_kernel<<<2048, 256, 0, stream>>>(ws, out);
    bbx_kernel<<<NB, 256, 0, stream>>>(ws, out);
}